// Round 1
// baseline (3390.776 us; speedup 1.0000x reference)
//
#include <hip/hip_runtime.h>
#include <cstdint>
#include <cstddef>

// SelfAttention: hs[4,2048,1024] fp32; Wq/Wk/Wv [1024,1024]; out = (ctx[4,2048,1024], probs[4,16,2048,2048])
// R0 baseline: all-fp32, 3 stages. Q/K/V staged in d_ws as [BH, S, 64] (~101 MB).

#define BB 4
#define SS 2048
#define HID 1024
#define NH 16
#define HD 64
#define MTOT (BB * SS)   // 8192
#define BH (BB * NH)     // 64

// ---------------- K1: y = X @ W^T + b, written as [BH, S, HD] ----------------
// X: [8192, 1024], W: [1024, 1024] row-major (nn.Linear weight), out[(b*16+h)*S + s][d], n = h*64+d
__global__ __launch_bounds__(256) void qkv_gemm(const float* __restrict__ X,
                                                const float* __restrict__ W,
                                                const float* __restrict__ bias,
                                                float* __restrict__ out) {
    __shared__ float As[16][68];  // [k][m], pad 68 (17 float4s: odd -> conflict-free b128)
    __shared__ float Bs[16][68];  // [k][n]
    const int t  = threadIdx.x;
    const int m0 = blockIdx.y * 64;
    const int n0 = blockIdx.x * 64;
    const int lr = t >> 2;         // 0..63
    const int lc = (t & 3) * 4;    // 0,4,8,12
    const int tr = (t >> 4) * 4;   // 0..60: acc rows
    const int tc = (t & 15) * 4;   // 0..60: acc cols

    float acc[4][4];
#pragma unroll
    for (int u = 0; u < 4; u++)
#pragma unroll
        for (int v = 0; v < 4; v++) acc[u][v] = 0.f;

    const float* Xp = X + (size_t)(m0 + lr) * HID + lc;
    const float* Wp = W + (size_t)(n0 + lr) * HID + lc;

    for (int k0 = 0; k0 < HID; k0 += 16) {
        float4 a = *(const float4*)(Xp + k0);
        float4 b = *(const float4*)(Wp + k0);
        __syncthreads();
        As[lc + 0][lr] = a.x; As[lc + 1][lr] = a.y; As[lc + 2][lr] = a.z; As[lc + 3][lr] = a.w;
        Bs[lc + 0][lr] = b.x; Bs[lc + 1][lr] = b.y; Bs[lc + 2][lr] = b.z; Bs[lc + 3][lr] = b.w;
        __syncthreads();
#pragma unroll
        for (int kk = 0; kk < 16; kk++) {
            float4 av = *(const float4*)&As[kk][tr];
            float4 bv = *(const float4*)&Bs[kk][tc];
            acc[0][0] += av.x * bv.x; acc[0][1] += av.x * bv.y; acc[0][2] += av.x * bv.z; acc[0][3] += av.x * bv.w;
            acc[1][0] += av.y * bv.x; acc[1][1] += av.y * bv.y; acc[1][2] += av.y * bv.z; acc[1][3] += av.y * bv.w;
            acc[2][0] += av.z * bv.x; acc[2][1] += av.z * bv.y; acc[2][2] += av.z * bv.z; acc[2][3] += av.z * bv.w;
            acc[3][0] += av.w * bv.x; acc[3][1] += av.w * bv.y; acc[3][2] += av.w * bv.z; acc[3][3] += av.w * bv.w;
        }
    }

    const int n_base = n0 + tc;
    const int h  = n_base >> 6;
    const int d0 = n_base & 63;  // d0..d0+3 stay within one head (tc mult of 4, 64|n0)
    const float4 bvec = *(const float4*)&bias[n_base];
#pragma unroll
    for (int u = 0; u < 4; u++) {
        const int m = m0 + tr + u;
        const int bb = m >> 11;          // /2048
        const int s  = m & (SS - 1);
        float4 r;
        r.x = acc[u][0] + bvec.x; r.y = acc[u][1] + bvec.y;
        r.z = acc[u][2] + bvec.z; r.w = acc[u][3] + bvec.w;
        *(float4*)&out[((size_t)(bb * NH + h) * SS + s) * HD + d0] = r;
    }
}

// ---------------- K2: attention: e=exp(qk/8+mask) -> probs (unnormalized), ctx=(e@v)/Z ----------------
__global__ __launch_bounds__(256) void attn(const float* __restrict__ Q,
                                            const float* __restrict__ K,
                                            const float* __restrict__ V,
                                            const float* __restrict__ mask,
                                            float* __restrict__ probs,
                                            float* __restrict__ ctx,
                                            float* __restrict__ invZ) {
    const int bh = blockIdx.x;            // fast dim -> same bh stays on one XCD (L2 locality for K/V)
    const int q0 = blockIdx.y * 32;
    const int b  = bh >> 4;
    const int h  = bh & 15;
    const int t  = threadIdx.x;

    __shared__ float q_lds[32][68];   // [i][c]
    __shared__ float kT[64][68];      // [c][j] (transposed)
    __shared__ float v_lds[64][68];   // [j][d]
    __shared__ float e_lds[32][68];   // [i][j]
    __shared__ float m_lds[64];

    // load q tile: thread -> (row t>>3, cols (t&7)*8 .. +7)
    {
        const int r = t >> 3, c0 = (t & 7) * 8;
        const float* gq = Q + ((size_t)bh * SS + q0 + r) * HD + c0;
        *(float4*)&q_lds[r][c0]     = *(const float4*)gq;
        *(float4*)&q_lds[r][c0 + 4] = *(const float4*)(gq + 4);
    }

    const int i  = t >> 3;          // 0..31 (q row)
    const int jc = (t & 7) * 4;     // chunk A: jc..jc+3, chunk B: jc+32..jc+35 (odd float4-stride -> no conflict)

    float ctx_acc[8];
#pragma unroll
    for (int u = 0; u < 8; u++) ctx_acc[u] = 0.f;
    float Zpart = 0.f;

    const float* Kb    = K + (size_t)bh * SS * HD;
    const float* Vb    = V + (size_t)bh * SS * HD;
    const float* maskb = mask + (size_t)b * SS;
    float* probs_row   = probs + ((size_t)bh * SS + q0 + i) * SS;

    const int lr = t >> 2;          // 0..63 staging row
    const int lc0 = (t & 3) * 16;   // 16 floats per thread

    for (int kt = 0; kt < SS; kt += 64) {
        __syncthreads();  // previous tile's LDS reads complete
        // stage K (transposed) and V (natural): 64x64 each
        {
            const float* kg = Kb + (size_t)(kt + lr) * HD + lc0;
            const float* vg = Vb + (size_t)(kt + lr) * HD + lc0;
#pragma unroll
            for (int ii = 0; ii < 4; ii++) {
                float4 kx = *(const float4*)(kg + ii * 4);
                kT[lc0 + ii * 4 + 0][lr] = kx.x;
                kT[lc0 + ii * 4 + 1][lr] = kx.y;
                kT[lc0 + ii * 4 + 2][lr] = kx.z;
                kT[lc0 + ii * 4 + 3][lr] = kx.w;
                *(float4*)&v_lds[lr][lc0 + ii * 4] = *(const float4*)(vg + ii * 4);
            }
            if (t < 64) m_lds[t] = maskb[kt + t];
        }
        __syncthreads();

        // QK^T: s[i][jc..], s[i][jc+32..]
        float sA[4] = {0.f, 0.f, 0.f, 0.f}, sB[4] = {0.f, 0.f, 0.f, 0.f};
#pragma unroll 8
        for (int c = 0; c < 64; c++) {
            const float qv = q_lds[i][c];
            const float4 ka = *(const float4*)&kT[c][jc];
            const float4 kb = *(const float4*)&kT[c][jc + 32];
            sA[0] += qv * ka.x; sA[1] += qv * ka.y; sA[2] += qv * ka.z; sA[3] += qv * ka.w;
            sB[0] += qv * kb.x; sB[1] += qv * kb.y; sB[2] += qv * kb.z; sB[3] += qv * kb.w;
        }
        // scores ~ N(0,1): exp without max-subtraction is safe in fp32
        float4 eA, eB;
        eA.x = __expf(sA[0] * 0.125f + m_lds[jc + 0]);
        eA.y = __expf(sA[1] * 0.125f + m_lds[jc + 1]);
        eA.z = __expf(sA[2] * 0.125f + m_lds[jc + 2]);
        eA.w = __expf(sA[3] * 0.125f + m_lds[jc + 3]);
        eB.x = __expf(sB[0] * 0.125f + m_lds[jc + 32]);
        eB.y = __expf(sB[1] * 0.125f + m_lds[jc + 33]);
        eB.z = __expf(sB[2] * 0.125f + m_lds[jc + 34]);
        eB.w = __expf(sB[3] * 0.125f + m_lds[jc + 35]);
        Zpart += eA.x + eA.y + eA.z + eA.w + eB.x + eB.y + eB.z + eB.w;
        *(float4*)&e_lds[i][jc]      = eA;
        *(float4*)&e_lds[i][jc + 32] = eB;
        *(float4*)(probs_row + kt + jc)      = eA;
        *(float4*)(probs_row + kt + jc + 32) = eB;
        __syncthreads();

        // PV: ctx[i][jc..], ctx[i][jc+32..] += e[i][j] * v[j][d]
#pragma unroll 8
        for (int j = 0; j < 64; j++) {
            const float ev = e_lds[i][j];
            const float4 va = *(const float4*)&v_lds[j][jc];
            const float4 vb = *(const float4*)&v_lds[j][jc + 32];
            ctx_acc[0] += ev * va.x; ctx_acc[1] += ev * va.y; ctx_acc[2] += ev * va.z; ctx_acc[3] += ev * va.w;
            ctx_acc[4] += ev * vb.x; ctx_acc[5] += ev * vb.y; ctx_acc[6] += ev * vb.z; ctx_acc[7] += ev * vb.w;
        }
    }

    // row sum across the 8 lanes sharing i (contiguous octet within a wave)
    Zpart += __shfl_xor(Zpart, 1);
    Zpart += __shfl_xor(Zpart, 2);
    Zpart += __shfl_xor(Zpart, 4);
    const float inv = 1.0f / Zpart;
    if ((t & 7) == 0) invZ[(size_t)bh * SS + q0 + i] = inv;

    float* gc = ctx + ((size_t)b * SS + q0 + i) * HID + h * HD;
    float4 ra, rb;
    ra.x = ctx_acc[0] * inv; ra.y = ctx_acc[1] * inv; ra.z = ctx_acc[2] * inv; ra.w = ctx_acc[3] * inv;
    rb.x = ctx_acc[4] * inv; rb.y = ctx_acc[5] * inv; rb.z = ctx_acc[6] * inv; rb.w = ctx_acc[7] * inv;
    *(float4*)(gc + jc)      = ra;
    *(float4*)(gc + jc + 32) = rb;
}

// ---------------- K3: probs *= invZ[row] ----------------
__global__ __launch_bounds__(256) void rescale(float* __restrict__ probs,
                                               const float* __restrict__ invZ) {
    const size_t total4 = (size_t)BH * SS * SS / 4;  // 67,108,864 float4s
    const size_t stride = (size_t)gridDim.x * 256;
    for (size_t p = (size_t)blockIdx.x * 256 + threadIdx.x; p < total4; p += stride) {
        const size_t row = p >> 9;  // 512 float4 per row of 2048
        const float iz = invZ[row];
        float4 v = ((const float4*)probs)[p];
        v.x *= iz; v.y *= iz; v.z *= iz; v.w *= iz;
        ((float4*)probs)[p] = v;
    }
}

extern "C" void kernel_launch(void* const* d_in, const int* in_sizes, int n_in,
                              void* d_out, int out_size, void* d_ws, size_t ws_size,
                              hipStream_t stream) {
    const float* hs   = (const float*)d_in[0];
    const float* mask = (const float*)d_in[1];
    const float* Wq   = (const float*)d_in[2];
    const float* bq   = (const float*)d_in[3];
    const float* Wk   = (const float*)d_in[4];
    const float* bk   = (const float*)d_in[5];
    const float* Wv   = (const float*)d_in[6];
    const float* bv   = (const float*)d_in[7];

    float* ctx   = (float*)d_out;
    float* probs = (float*)d_out + (size_t)BB * SS * HID;  // 8,388,608 floats in

    const size_t qkv_elems = (size_t)BH * SS * HD;  // 8,388,608
    float* Qw   = (float*)d_ws;
    float* Kw   = Qw + qkv_elems;
    float* Vw   = Kw + qkv_elems;
    float* invZ = Vw + qkv_elems;  // BH*SS floats
    (void)ws_size; (void)in_sizes; (void)n_in; (void)out_size;

    dim3 gproj(HID / 64, MTOT / 64);  // (16, 128)
    qkv_gemm<<<gproj, 256, 0, stream>>>(hs, Wq, bq, Qw);
    qkv_gemm<<<gproj, 256, 0, stream>>>(hs, Wk, bk, Kw);
    qkv_gemm<<<gproj, 256, 0, stream>>>(hs, Wv, bv, Vw);

    dim3 gattn(BH, SS / 32);  // (64, 64)
    attn<<<gattn, 256, 0, stream>>>(Qw, Kw, Vw, mask, probs, ctx, invZ);

    rescale<<<32768, 256, 0, stream>>>(probs, invZ);
}